// Round 5
// baseline (327.347 us; speedup 1.0000x reference)
//
#include <hip/hip_runtime.h>
#include <hip/hip_bf16.h>

#define BATCH 4
#define S_LEN 2048
#define D_DIM 1024
#define NHEAD 16
#define HDIM 64

// Q pre-scale: 1/sqrt(HDIM) * log2(e), so softmax works in exp2 domain.
#define QSCALE 0.18033688011112042f

typedef __attribute__((ext_vector_type(8))) __bf16 bf16x8;
typedef __attribute__((ext_vector_type(4))) __bf16 bf16x4;
typedef __attribute__((ext_vector_type(4))) float f32x4;

static __device__ inline unsigned int bf16_bits(float f) {
    __bf16 h = (__bf16)f;
    return (unsigned int)__builtin_bit_cast(unsigned short, h);
}

// ---------------------------------------------------------------------------
// fp32 -> bf16 bulk convert, 8 elems/thread, 16B stores.
// ---------------------------------------------------------------------------
__global__ __launch_bounds__(256) void cvt_kernel(
    const float* __restrict__ src, __bf16* __restrict__ dst, int n8)
{
    int i = blockIdx.x * 256 + threadIdx.x;
    if (i >= n8) return;
    const f32x4* p = reinterpret_cast<const f32x4*>(src + (size_t)i * 8);
    f32x4 a = p[0], b = p[1];
    bf16x8 r;
    r[0] = (__bf16)a[0]; r[1] = (__bf16)a[1]; r[2] = (__bf16)a[2]; r[3] = (__bf16)a[3];
    r[4] = (__bf16)b[0]; r[5] = (__bf16)b[1]; r[6] = (__bf16)b[2]; r[7] = (__bf16)b[3];
    *reinterpret_cast<bf16x8*>(dst + (size_t)i * 8) = r;
}

// ---------------------------------------------------------------------------
// Projection GEMM (m97-style): C[m][n] = sum_d xb[m][d] * wb[n][d]
// q output is pre-scaled by QSCALE. q,k -> [bh][s][e]; v -> [bh][e][s].
// ---------------------------------------------------------------------------
__global__ __launch_bounds__(256) void proj_gemm_kernel(
    const __bf16* __restrict__ xb, const __bf16* __restrict__ wb,
    __bf16* __restrict__ qo, __bf16* __restrict__ ko, __bf16* __restrict__ vto)
{
    __shared__ __bf16 As[128][32];
    __shared__ __bf16 Bs[128][32];

    const int tid = threadIdx.x;
    const int l  = tid & 63;
    const int w  = tid >> 6;
    const int wm = w >> 1, wn = w & 1;
    const int lr = l & 15, lg = l >> 4, lk = lg * 8;
    const int m0 = blockIdx.y * 128;
    const int n0 = blockIdx.x * 128;
    const int mat = n0 >> 10;           // 0=q,1=k,2=v
    const int nb  = n0 & 1023;

    const int sr = l >> 2;
    const int sc = (l & 3) * 8;
    const int g0 = w * 2;

    f32x4 acc[4][4] = {};

    for (int d = 0; d < D_DIM; d += 32) {
        __builtin_amdgcn_global_load_lds(
            (const __attribute__((address_space(1))) void*)(xb + (size_t)(m0 + g0 * 16 + sr) * D_DIM + d + sc),
            (__attribute__((address_space(3))) void*)(&As[g0 * 16][0]), 16, 0, 0);
        __builtin_amdgcn_global_load_lds(
            (const __attribute__((address_space(1))) void*)(xb + (size_t)(m0 + (g0 + 1) * 16 + sr) * D_DIM + d + sc),
            (__attribute__((address_space(3))) void*)(&As[(g0 + 1) * 16][0]), 16, 0, 0);
        __builtin_amdgcn_global_load_lds(
            (const __attribute__((address_space(1))) void*)(wb + (size_t)(n0 + g0 * 16 + sr) * D_DIM + d + sc),
            (__attribute__((address_space(3))) void*)(&Bs[g0 * 16][0]), 16, 0, 0);
        __builtin_amdgcn_global_load_lds(
            (const __attribute__((address_space(1))) void*)(wb + (size_t)(n0 + (g0 + 1) * 16 + sr) * D_DIM + d + sc),
            (__attribute__((address_space(3))) void*)(&Bs[(g0 + 1) * 16][0]), 16, 0, 0);
        __syncthreads();

        bf16x8 af[4], bfr[4];
        #pragma unroll
        for (int mi = 0; mi < 4; ++mi)
            af[mi] = *reinterpret_cast<const bf16x8*>(&As[wm * 64 + mi * 16 + lr][lk]);
        #pragma unroll
        for (int ni = 0; ni < 4; ++ni)
            bfr[ni] = *reinterpret_cast<const bf16x8*>(&Bs[wn * 64 + ni * 16 + lr][lk]);
        #pragma unroll
        for (int mi = 0; mi < 4; ++mi) {
            #pragma unroll
            for (int ni = 0; ni < 4; ++ni)
                acc[mi][ni] = __builtin_amdgcn_mfma_f32_16x16x32_bf16(
                    af[mi], bfr[ni], acc[mi][ni], 0, 0, 0);
        }
        __syncthreads();
    }

    const float oscale = (mat == 0) ? QSCALE : 1.0f;
    #pragma unroll
    for (int mi = 0; mi < 4; ++mi) {
        const int mrow = m0 + wm * 64 + mi * 16 + lg * 4;
        const int b = mrow >> 11;
        const int s = mrow & (S_LEN - 1);
        #pragma unroll
        for (int ni = 0; ni < 4; ++ni) {
            const int n = nb + wn * 64 + ni * 16 + lr;
            const int h = n >> 6;
            const int e = n & 63;
            if (mat == 2) {
                bf16x4 pk;
                #pragma unroll
                for (int r = 0; r < 4; ++r) pk[r] = (__bf16)acc[mi][ni][r];
                *reinterpret_cast<bf16x4*>(
                    vto + ((size_t)(b * NHEAD + h) * HDIM + e) * S_LEN + s) = pk;
            } else {
                __bf16* __restrict__ dst = (mat == 0) ? qo : ko;
                #pragma unroll
                for (int r = 0; r < 4; ++r)
                    dst[((size_t)(b * NHEAD + h) * S_LEN + (s + r)) * HDIM + e] =
                        (__bf16)(acc[mi][ni][r] * oscale);
            }
        }
    }
}

// ---------------------------------------------------------------------------
// Causal flash attention: single 16-row q-tile per 1-wave block.
// Swapped QK^T (lane holds 16 kv scores of ONE q-row = qw + lane&15) and
// swapped PV (acc col = own q-row: no broadcast shfls). Defer-max skips the
// cross-lane max reduce + rescale when the tile max grew <= 2^8.
// Grid: 8192 waves, LPT (tile 127 first), heads pinned to XCDs.
// ---------------------------------------------------------------------------
__global__ __launch_bounds__(64, 8) void attn_kernel(
    const __bf16* __restrict__ q, const __bf16* __restrict__ k,
    const __bf16* __restrict__ vt, float* __restrict__ out)
{
    __shared__ __bf16 plds[16][64];

    const int l  = threadIdx.x;
    const int lr = l & 15;
    const int lg = l >> 4;
    const int lk = lg * 8;
    const int swz = (lr & 7) << 3;

    // LPT decode: per XCD, all 8 heads do tile 127, then 126, ...
    const int n   = blockIdx.x;
    const int xcd = n & 7;
    const int m   = n >> 3;              // 0..1023
    const int t   = 127 - (m >> 3);      // q-tile index (16 rows)
    const int bh  = xcd * 8 + (m & 7);

    const __bf16* __restrict__ kp = k  + (size_t)bh * S_LEN * HDIM;
    const __bf16* __restrict__ vp = vt + (size_t)bh * HDIM * S_LEN;
    const int bq = bh >> 4;
    const int hq = bh & 15;

    const int qw = t * 16;
    const int iters = (t >> 2) + 1;      // ceil((16t+16)/64)

    const __bf16* __restrict__ qp = q + ((size_t)bh * S_LEN + qw) * HDIM;
    const bf16x8 bq0 = *reinterpret_cast<const bf16x8*>(qp + lr * HDIM + lk);
    const bf16x8 bq1 = *reinterpret_cast<const bf16x8*>(qp + lr * HDIM + 32 + lk);

    float m_acc = -1e30f, l_acc = 0.0f;
    f32x4 acc[4] = {};
    __bf16* pl = &plds[0][0];

    for (int j = 0; j < iters; ++j) {
        const int kv0 = j * 64;

        // ---- QK^T (swapped): s[c][r] for kv = kv0 + c*16 + lg*4 + r ----
        f32x4 s[4];
        __builtin_amdgcn_s_setprio(1);
        #pragma unroll
        for (int c = 0; c < 4; ++c) {
            const __bf16* krow = kp + (size_t)(kv0 + c * 16 + lr) * HDIM;
            const bf16x8 ka0 = *reinterpret_cast<const bf16x8*>(krow + lk);
            const bf16x8 ka1 = *reinterpret_cast<const bf16x8*>(krow + 32 + lk);
            f32x4 tt = {};
            tt = __builtin_amdgcn_mfma_f32_16x16x32_bf16(ka0, bq0, tt, 0, 0, 0);
            tt = __builtin_amdgcn_mfma_f32_16x16x32_bf16(ka1, bq1, tt, 0, 0, 0);
            s[c] = tt;
        }
        __builtin_amdgcn_s_setprio(0);

        // ---- causal mask in place (diagonal iterations only) ----
        if (kv0 + 63 > qw) {             // wave-uniform
            const int qrow = qw + lr;
            #pragma unroll
            for (int c = 0; c < 4; ++c)
                #pragma unroll
                for (int r = 0; r < 4; ++r)
                    if (kv0 + c * 16 + lg * 4 + r > qrow) s[c][r] = -1e30f;
        }

        // ---- lane-local max (16 values) ----
        float a0 = fmaxf(fmaxf(s[0][0], s[0][1]), fmaxf(s[0][2], s[0][3]));
        float a1 = fmaxf(fmaxf(s[1][0], s[1][1]), fmaxf(s[1][2], s[1][3]));
        float a2 = fmaxf(fmaxf(s[2][0], s[2][1]), fmaxf(s[2][2], s[2][3]));
        float a3 = fmaxf(fmaxf(s[3][0], s[3][1]), fmaxf(s[3][2], s[3][3]));
        float mx = fmaxf(fmaxf(a0, a1), fmaxf(a2, a3));

        // ---- defer-max: skip reduce + rescale when growth <= 2^8 ----
        if (!__all(mx - m_acc <= 8.0f)) {
            mx = fmaxf(mx, __shfl_xor(mx, 16));
            mx = fmaxf(mx, __shfl_xor(mx, 32));
            const float mnew = fmaxf(m_acc, mx);
            const float sc = exp2f(m_acc - mnew);
            l_acc *= sc;
            #pragma unroll
            for (int ni = 0; ni < 4; ++ni) acc[ni] *= sc;
            m_acc = mnew;
        }

        // ---- P = exp2(s - m), pack + store immediately (low reg pressure) ----
        float psum = 0.0f;
        #pragma unroll
        for (int c = 0; c < 4; ++c) {
            const float p0 = exp2f(s[c][0] - m_acc);
            const float p1 = exp2f(s[c][1] - m_acc);
            const float p2 = exp2f(s[c][2] - m_acc);
            const float p3 = exp2f(s[c][3] - m_acc);
            psum += (p0 + p1) + (p2 + p3);
            uint2 pk;
            pk.x = bf16_bits(p0) | (bf16_bits(p1) << 16);
            pk.y = bf16_bits(p2) | (bf16_bits(p3) << 16);
            *reinterpret_cast<uint2*>(pl + lr * 64 + ((c * 16 + lg * 4) ^ swz)) = pk;
        }
        psum += __shfl_xor(psum, 16);
        psum += __shfl_xor(psum, 32);
        l_acc += psum;

        // ---- PV (swapped): acc[ni] cols = own q-row ----
        __builtin_amdgcn_s_setprio(1);
        #pragma unroll
        for (int c2 = 0; c2 < 2; ++c2) {
            const bf16x8 pa = *reinterpret_cast<const bf16x8*>(
                pl + lr * 64 + ((c2 * 32 + lk) ^ swz));
            #pragma unroll
            for (int ni = 0; ni < 4; ++ni) {
                const bf16x8 av = *reinterpret_cast<const bf16x8*>(
                    vp + (size_t)(ni * 16 + lr) * S_LEN + kv0 + c2 * 32 + lk);
                acc[ni] = __builtin_amdgcn_mfma_f32_16x16x32_bf16(av, pa, acc[ni], 0, 0, 0);
            }
        }
        __builtin_amdgcn_s_setprio(0);
    }

    // ---- epilogue: lane's q-row = qw + lr; e = ni*16 + lg*4 + r ----
    const float liv = 1.0f / l_acc;
    float* orow = out + (size_t)(bq * S_LEN + qw + lr) * D_DIM + hq * HDIM;
    #pragma unroll
    for (int ni = 0; ni < 4; ++ni) {
        f32x4 ox;
        #pragma unroll
        for (int r = 0; r < 4; ++r) ox[r] = acc[ni][r] * liv;
        *reinterpret_cast<f32x4*>(orow + ni * 16 + lg * 4) = ox;
    }
}

extern "C" void kernel_launch(void* const* d_in, const int* in_sizes, int n_in,
                              void* d_out, int out_size, void* d_ws, size_t ws_size,
                              hipStream_t stream)
{
    const float* x  = (const float*)d_in[0];
    const float* Wq = (const float*)d_in[1];
    const float* Wk = (const float*)d_in[2];
    const float* Wv = (const float*)d_in[3];
    float* out = (float*)d_out;

    const size_t x_elems = (size_t)BATCH * S_LEN * D_DIM;
    const size_t w_elems = (size_t)D_DIM * D_DIM;
    __bf16* xb   = (__bf16*)d_out;          // scratch in d_out (overwritten)
    __bf16* wcat = xb + x_elems;

    const size_t per_buf = (size_t)BATCH * NHEAD * S_LEN * HDIM;
    __bf16* qb = (__bf16*)d_ws;
    __bf16* kb = qb + per_buf;
    __bf16* vb = kb + per_buf;

    cvt_kernel<<<(int)(x_elems / 8 / 256), 256, 0, stream>>>(x, xb, (int)(x_elems / 8));
    cvt_kernel<<<(int)(w_elems / 8 / 256), 256, 0, stream>>>(Wq, wcat, (int)(w_elems / 8));
    cvt_kernel<<<(int)(w_elems / 8 / 256), 256, 0, stream>>>(Wk, wcat + w_elems, (int)(w_elems / 8));
    cvt_kernel<<<(int)(w_elems / 8 / 256), 256, 0, stream>>>(Wv, wcat + 2 * w_elems, (int)(w_elems / 8));

    dim3 grid1(3 * D_DIM / 128, (BATCH * S_LEN) / 128);   // (24, 64)
    proj_gemm_kernel<<<grid1, dim3(256), 0, stream>>>(xb, wcat, qb, kb, vb);

    attn_kernel<<<dim3(8192), dim3(64), 0, stream>>>(qb, kb, vb, out);
}

// Round 6
// 322.414 us; speedup vs baseline: 1.0153x; 1.0153x over previous
//
#include <hip/hip_runtime.h>
#include <hip/hip_bf16.h>

#define BATCH 4
#define S_LEN 2048
#define D_DIM 1024
#define NHEAD 16
#define HDIM 64

// Q pre-scale: 1/sqrt(HDIM) * log2(e), so softmax works in exp2 domain.
#define QSCALE 0.18033688011112042f

typedef __attribute__((ext_vector_type(8))) __bf16 bf16x8;
typedef __attribute__((ext_vector_type(4))) __bf16 bf16x4;
typedef __attribute__((ext_vector_type(4))) float f32x4;

static __device__ inline unsigned int bf16_bits(float f) {
    __bf16 h = (__bf16)f;
    return (unsigned int)__builtin_bit_cast(unsigned short, h);
}

// ---------------------------------------------------------------------------
// fp32 -> bf16 bulk convert, 8 elems/thread, 16B stores.
// ---------------------------------------------------------------------------
__global__ __launch_bounds__(256) void cvt_kernel(
    const float* __restrict__ src, __bf16* __restrict__ dst, int n8)
{
    int i = blockIdx.x * 256 + threadIdx.x;
    if (i >= n8) return;
    const f32x4* p = reinterpret_cast<const f32x4*>(src + (size_t)i * 8);
    f32x4 a = p[0], b = p[1];
    bf16x8 r;
    r[0] = (__bf16)a[0]; r[1] = (__bf16)a[1]; r[2] = (__bf16)a[2]; r[3] = (__bf16)a[3];
    r[4] = (__bf16)b[0]; r[5] = (__bf16)b[1]; r[6] = (__bf16)b[2]; r[7] = (__bf16)b[3];
    *reinterpret_cast<bf16x8*>(dst + (size_t)i * 8) = r;
}

// ---------------------------------------------------------------------------
// Projection GEMM (m97-style): C[m][n] = sum_d xb[m][d] * wb[n][d]
// q output is pre-scaled by QSCALE. q,k -> [bh][s][e]; v -> [bh][e][s].
// ---------------------------------------------------------------------------
__global__ __launch_bounds__(256) void proj_gemm_kernel(
    const __bf16* __restrict__ xb, const __bf16* __restrict__ wb,
    __bf16* __restrict__ qo, __bf16* __restrict__ ko, __bf16* __restrict__ vto)
{
    __shared__ __bf16 As[128][32];
    __shared__ __bf16 Bs[128][32];

    const int tid = threadIdx.x;
    const int l  = tid & 63;
    const int w  = tid >> 6;
    const int wm = w >> 1, wn = w & 1;
    const int lr = l & 15, lg = l >> 4, lk = lg * 8;
    const int m0 = blockIdx.y * 128;
    const int n0 = blockIdx.x * 128;
    const int mat = n0 >> 10;           // 0=q,1=k,2=v
    const int nb  = n0 & 1023;

    const int sr = l >> 2;
    const int sc = (l & 3) * 8;
    const int g0 = w * 2;

    f32x4 acc[4][4] = {};

    for (int d = 0; d < D_DIM; d += 32) {
        __builtin_amdgcn_global_load_lds(
            (const __attribute__((address_space(1))) void*)(xb + (size_t)(m0 + g0 * 16 + sr) * D_DIM + d + sc),
            (__attribute__((address_space(3))) void*)(&As[g0 * 16][0]), 16, 0, 0);
        __builtin_amdgcn_global_load_lds(
            (const __attribute__((address_space(1))) void*)(xb + (size_t)(m0 + (g0 + 1) * 16 + sr) * D_DIM + d + sc),
            (__attribute__((address_space(3))) void*)(&As[(g0 + 1) * 16][0]), 16, 0, 0);
        __builtin_amdgcn_global_load_lds(
            (const __attribute__((address_space(1))) void*)(wb + (size_t)(n0 + g0 * 16 + sr) * D_DIM + d + sc),
            (__attribute__((address_space(3))) void*)(&Bs[g0 * 16][0]), 16, 0, 0);
        __builtin_amdgcn_global_load_lds(
            (const __attribute__((address_space(1))) void*)(wb + (size_t)(n0 + (g0 + 1) * 16 + sr) * D_DIM + d + sc),
            (__attribute__((address_space(3))) void*)(&Bs[(g0 + 1) * 16][0]), 16, 0, 0);
        __syncthreads();

        bf16x8 af[4], bfr[4];
        #pragma unroll
        for (int mi = 0; mi < 4; ++mi)
            af[mi] = *reinterpret_cast<const bf16x8*>(&As[wm * 64 + mi * 16 + lr][lk]);
        #pragma unroll
        for (int ni = 0; ni < 4; ++ni)
            bfr[ni] = *reinterpret_cast<const bf16x8*>(&Bs[wn * 64 + ni * 16 + lr][lk]);
        #pragma unroll
        for (int mi = 0; mi < 4; ++mi) {
            #pragma unroll
            for (int ni = 0; ni < 4; ++ni)
                acc[mi][ni] = __builtin_amdgcn_mfma_f32_16x16x32_bf16(
                    af[mi], bfr[ni], acc[mi][ni], 0, 0, 0);
        }
        __syncthreads();
    }

    const float oscale = (mat == 0) ? QSCALE : 1.0f;
    #pragma unroll
    for (int mi = 0; mi < 4; ++mi) {
        const int mrow = m0 + wm * 64 + mi * 16 + lg * 4;
        const int b = mrow >> 11;
        const int s = mrow & (S_LEN - 1);
        #pragma unroll
        for (int ni = 0; ni < 4; ++ni) {
            const int n = nb + wn * 64 + ni * 16 + lr;
            const int h = n >> 6;
            const int e = n & 63;
            if (mat == 2) {
                bf16x4 pk;
                #pragma unroll
                for (int r = 0; r < 4; ++r) pk[r] = (__bf16)acc[mi][ni][r];
                *reinterpret_cast<bf16x4*>(
                    vto + ((size_t)(b * NHEAD + h) * HDIM + e) * S_LEN + s) = pk;
            } else {
                __bf16* __restrict__ dst = (mat == 0) ? qo : ko;
                #pragma unroll
                for (int r = 0; r < 4; ++r)
                    dst[((size_t)(b * NHEAD + h) * S_LEN + (s + r)) * HDIM + e] =
                        (__bf16)(acc[mi][ni][r] * oscale);
            }
        }
    }
}

// ---------------------------------------------------------------------------
// Causal flash attention: single 16-row q-tile per 1-wave block.
// Swapped QK^T (lane holds 16 kv scores of ONE q-row = qw + lane&15) and
// swapped PV (acc col = own q-row: no broadcast shfls). Defer-max skips the
// cross-lane max reduce + rescale when the tile max grew <= 2^8.
// Grid: 8192 waves (1.6x oversubscribed at 5 waves/EU -> backfill), LPT
// (tile 127 first), heads pinned to XCDs.
// launch_bounds(64,5): ~102-reg budget -> no spill (R5's (64,8) spilled:
// VGPR 32 + 8MB scratch writes, attn 164->259us).
// ---------------------------------------------------------------------------
__global__ __launch_bounds__(64, 5) void attn_kernel(
    const __bf16* __restrict__ q, const __bf16* __restrict__ k,
    const __bf16* __restrict__ vt, float* __restrict__ out)
{
    __shared__ __bf16 plds[16][64];

    const int l  = threadIdx.x;
    const int lr = l & 15;
    const int lg = l >> 4;
    const int lk = lg * 8;
    const int swz = (lr & 7) << 3;

    // LPT decode: per XCD, all 8 heads do tile 127, then 126, ...
    const int n   = blockIdx.x;
    const int xcd = n & 7;
    const int m   = n >> 3;              // 0..1023
    const int t   = 127 - (m >> 3);      // q-tile index (16 rows)
    const int bh  = xcd * 8 + (m & 7);

    const __bf16* __restrict__ kp = k  + (size_t)bh * S_LEN * HDIM;
    const __bf16* __restrict__ vp = vt + (size_t)bh * HDIM * S_LEN;
    const int bq = bh >> 4;
    const int hq = bh & 15;

    const int qw = t * 16;
    const int iters = (t >> 2) + 1;      // ceil((16t+16)/64)

    const __bf16* __restrict__ qp = q + ((size_t)bh * S_LEN + qw) * HDIM;
    const bf16x8 bq0 = *reinterpret_cast<const bf16x8*>(qp + lr * HDIM + lk);
    const bf16x8 bq1 = *reinterpret_cast<const bf16x8*>(qp + lr * HDIM + 32 + lk);

    float m_acc = -1e30f, l_acc = 0.0f;
    f32x4 acc[4] = {};
    __bf16* pl = &plds[0][0];

    #pragma unroll 1
    for (int j = 0; j < iters; ++j) {
        const int kv0 = j * 64;

        // ---- QK^T (swapped): s[c][r] for kv = kv0 + c*16 + lg*4 + r ----
        f32x4 s[4];
        __builtin_amdgcn_s_setprio(1);
        #pragma unroll
        for (int c = 0; c < 4; ++c) {
            const __bf16* krow = kp + (size_t)(kv0 + c * 16 + lr) * HDIM;
            const bf16x8 ka0 = *reinterpret_cast<const bf16x8*>(krow + lk);
            const bf16x8 ka1 = *reinterpret_cast<const bf16x8*>(krow + 32 + lk);
            f32x4 tt = {};
            tt = __builtin_amdgcn_mfma_f32_16x16x32_bf16(ka0, bq0, tt, 0, 0, 0);
            tt = __builtin_amdgcn_mfma_f32_16x16x32_bf16(ka1, bq1, tt, 0, 0, 0);
            s[c] = tt;
        }
        __builtin_amdgcn_s_setprio(0);

        // ---- causal mask in place (diagonal iteration only) ----
        if (kv0 + 63 > qw) {             // wave-uniform
            const int qrow = qw + lr;
            #pragma unroll
            for (int c = 0; c < 4; ++c)
                #pragma unroll
                for (int r = 0; r < 4; ++r)
                    if (kv0 + c * 16 + lg * 4 + r > qrow) s[c][r] = -1e30f;
        }

        // ---- lane-local max (16 values) ----
        float a0 = fmaxf(fmaxf(s[0][0], s[0][1]), fmaxf(s[0][2], s[0][3]));
        float a1 = fmaxf(fmaxf(s[1][0], s[1][1]), fmaxf(s[1][2], s[1][3]));
        float a2 = fmaxf(fmaxf(s[2][0], s[2][1]), fmaxf(s[2][2], s[2][3]));
        float a3 = fmaxf(fmaxf(s[3][0], s[3][1]), fmaxf(s[3][2], s[3][3]));
        float mx = fmaxf(fmaxf(a0, a1), fmaxf(a2, a3));

        // ---- defer-max: skip reduce + rescale when growth <= 2^8 ----
        if (!__all(mx - m_acc <= 8.0f)) {
            mx = fmaxf(mx, __shfl_xor(mx, 16));
            mx = fmaxf(mx, __shfl_xor(mx, 32));
            const float mnew = fmaxf(m_acc, mx);
            const float sc = exp2f(m_acc - mnew);
            l_acc *= sc;
            #pragma unroll
            for (int ni = 0; ni < 4; ++ni) acc[ni] *= sc;
            m_acc = mnew;
        }

        // ---- P = exp2(s - m), pack + store immediately (low reg pressure) ----
        float psum = 0.0f;
        #pragma unroll
        for (int c = 0; c < 4; ++c) {
            const float p0 = exp2f(s[c][0] - m_acc);
            const float p1 = exp2f(s[c][1] - m_acc);
            const float p2 = exp2f(s[c][2] - m_acc);
            const float p3 = exp2f(s[c][3] - m_acc);
            psum += (p0 + p1) + (p2 + p3);
            uint2 pk;
            pk.x = bf16_bits(p0) | (bf16_bits(p1) << 16);
            pk.y = bf16_bits(p2) | (bf16_bits(p3) << 16);
            *reinterpret_cast<uint2*>(pl + lr * 64 + ((c * 16 + lg * 4) ^ swz)) = pk;
        }
        psum += __shfl_xor(psum, 16);
        psum += __shfl_xor(psum, 32);
        l_acc += psum;

        // ---- PV (swapped): acc[ni] cols = own q-row ----
        __builtin_amdgcn_s_setprio(1);
        #pragma unroll
        for (int c2 = 0; c2 < 2; ++c2) {
            const bf16x8 pa = *reinterpret_cast<const bf16x8*>(
                pl + lr * 64 + ((c2 * 32 + lk) ^ swz));
            #pragma unroll
            for (int ni = 0; ni < 4; ++ni) {
                const bf16x8 av = *reinterpret_cast<const bf16x8*>(
                    vp + (size_t)(ni * 16 + lr) * S_LEN + kv0 + c2 * 32 + lk);
                acc[ni] = __builtin_amdgcn_mfma_f32_16x16x32_bf16(av, pa, acc[ni], 0, 0, 0);
            }
        }
        __builtin_amdgcn_s_setprio(0);
    }

    // ---- epilogue: lane's q-row = qw + lr; e = ni*16 + lg*4 + r ----
    const float liv = 1.0f / l_acc;
    float* orow = out + (size_t)(bq * S_LEN + qw + lr) * D_DIM + hq * HDIM;
    #pragma unroll
    for (int ni = 0; ni < 4; ++ni) {
        f32x4 ox;
        #pragma unroll
        for (int r = 0; r < 4; ++r) ox[r] = acc[ni][r] * liv;
        *reinterpret_cast<f32x4*>(orow + ni * 16 + lg * 4) = ox;
    }
}

extern "C" void kernel_launch(void* const* d_in, const int* in_sizes, int n_in,
                              void* d_out, int out_size, void* d_ws, size_t ws_size,
                              hipStream_t stream)
{
    const float* x  = (const float*)d_in[0];
    const float* Wq = (const float*)d_in[1];
    const float* Wk = (const float*)d_in[2];
    const float* Wv = (const float*)d_in[3];
    float* out = (float*)d_out;

    const size_t x_elems = (size_t)BATCH * S_LEN * D_DIM;
    const size_t w_elems = (size_t)D_DIM * D_DIM;
    __bf16* xb   = (__bf16*)d_out;          // scratch in d_out (overwritten)
    __bf16* wcat = xb + x_elems;

    const size_t per_buf = (size_t)BATCH * NHEAD * S_LEN * HDIM;
    __bf16* qb = (__bf16*)d_ws;
    __bf16* kb = qb + per_buf;
    __bf16* vb = kb + per_buf;

    cvt_kernel<<<(int)(x_elems / 8 / 256), 256, 0, stream>>>(x, xb, (int)(x_elems / 8));
    cvt_kernel<<<(int)(w_elems / 8 / 256), 256, 0, stream>>>(Wq, wcat, (int)(w_elems / 8));
    cvt_kernel<<<(int)(w_elems / 8 / 256), 256, 0, stream>>>(Wk, wcat + w_elems, (int)(w_elems / 8));
    cvt_kernel<<<(int)(w_elems / 8 / 256), 256, 0, stream>>>(Wv, wcat + 2 * w_elems, (int)(w_elems / 8));

    dim3 grid1(3 * D_DIM / 128, (BATCH * S_LEN) / 128);   // (24, 64)
    proj_gemm_kernel<<<grid1, dim3(256), 0, stream>>>(xb, wcat, qb, kb, vb);

    attn_kernel<<<dim3(8192), dim3(64), 0, stream>>>(qb, kb, vb, out);
}

// Round 7
// 193.015 us; speedup vs baseline: 1.6960x; 1.6704x over previous
//
#include <hip/hip_runtime.h>
#include <hip/hip_bf16.h>

#define BATCH 4
#define S_LEN 2048
#define D_DIM 1024
#define NHEAD 16
#define HDIM 64

// Q pre-scale: 1/sqrt(HDIM) * log2(e), so softmax works in exp2 domain.
#define QSCALE 0.18033688011112042f

typedef __attribute__((ext_vector_type(8))) __bf16 bf16x8;
typedef __attribute__((ext_vector_type(4))) __bf16 bf16x4;
typedef __attribute__((ext_vector_type(4))) float f32x4;

static __device__ inline unsigned int bf16_bits(float f) {
    __bf16 h = (__bf16)f;
    return (unsigned int)__builtin_bit_cast(unsigned short, h);
}

// ---------------------------------------------------------------------------
// fp32 -> bf16 bulk convert, 8 elems/thread, 16B stores.
// ---------------------------------------------------------------------------
__global__ __launch_bounds__(256) void cvt_kernel(
    const float* __restrict__ src, __bf16* __restrict__ dst, int n8)
{
    int i = blockIdx.x * 256 + threadIdx.x;
    if (i >= n8) return;
    const f32x4* p = reinterpret_cast<const f32x4*>(src + (size_t)i * 8);
    f32x4 a = p[0], b = p[1];
    bf16x8 r;
    r[0] = (__bf16)a[0]; r[1] = (__bf16)a[1]; r[2] = (__bf16)a[2]; r[3] = (__bf16)a[3];
    r[4] = (__bf16)b[0]; r[5] = (__bf16)b[1]; r[6] = (__bf16)b[2]; r[7] = (__bf16)b[3];
    *reinterpret_cast<bf16x8*>(dst + (size_t)i * 8) = r;
}

// ---------------------------------------------------------------------------
// Projection GEMM (m97-style): C[m][n] = sum_d xb[m][d] * wb[n][d]
// q output is pre-scaled by QSCALE. q,k -> [bh][s][e]; v -> [bh][e][s].
// ---------------------------------------------------------------------------
__global__ __launch_bounds__(256) void proj_gemm_kernel(
    const __bf16* __restrict__ xb, const __bf16* __restrict__ wb,
    __bf16* __restrict__ qo, __bf16* __restrict__ ko, __bf16* __restrict__ vto)
{
    __shared__ __bf16 As[128][32];
    __shared__ __bf16 Bs[128][32];

    const int tid = threadIdx.x;
    const int l  = tid & 63;
    const int w  = tid >> 6;
    const int wm = w >> 1, wn = w & 1;
    const int lr = l & 15, lg = l >> 4, lk = lg * 8;
    const int m0 = blockIdx.y * 128;
    const int n0 = blockIdx.x * 128;
    const int mat = n0 >> 10;           // 0=q,1=k,2=v
    const int nb  = n0 & 1023;

    const int sr = l >> 2;
    const int sc = (l & 3) * 8;
    const int g0 = w * 2;

    f32x4 acc[4][4] = {};

    for (int d = 0; d < D_DIM; d += 32) {
        __builtin_amdgcn_global_load_lds(
            (const __attribute__((address_space(1))) void*)(xb + (size_t)(m0 + g0 * 16 + sr) * D_DIM + d + sc),
            (__attribute__((address_space(3))) void*)(&As[g0 * 16][0]), 16, 0, 0);
        __builtin_amdgcn_global_load_lds(
            (const __attribute__((address_space(1))) void*)(xb + (size_t)(m0 + (g0 + 1) * 16 + sr) * D_DIM + d + sc),
            (__attribute__((address_space(3))) void*)(&As[(g0 + 1) * 16][0]), 16, 0, 0);
        __builtin_amdgcn_global_load_lds(
            (const __attribute__((address_space(1))) void*)(wb + (size_t)(n0 + g0 * 16 + sr) * D_DIM + d + sc),
            (__attribute__((address_space(3))) void*)(&Bs[g0 * 16][0]), 16, 0, 0);
        __builtin_amdgcn_global_load_lds(
            (const __attribute__((address_space(1))) void*)(wb + (size_t)(n0 + (g0 + 1) * 16 + sr) * D_DIM + d + sc),
            (__attribute__((address_space(3))) void*)(&Bs[(g0 + 1) * 16][0]), 16, 0, 0);
        __syncthreads();

        bf16x8 af[4], bfr[4];
        #pragma unroll
        for (int mi = 0; mi < 4; ++mi)
            af[mi] = *reinterpret_cast<const bf16x8*>(&As[wm * 64 + mi * 16 + lr][lk]);
        #pragma unroll
        for (int ni = 0; ni < 4; ++ni)
            bfr[ni] = *reinterpret_cast<const bf16x8*>(&Bs[wn * 64 + ni * 16 + lr][lk]);
        #pragma unroll
        for (int mi = 0; mi < 4; ++mi) {
            #pragma unroll
            for (int ni = 0; ni < 4; ++ni)
                acc[mi][ni] = __builtin_amdgcn_mfma_f32_16x16x32_bf16(
                    af[mi], bfr[ni], acc[mi][ni], 0, 0, 0);
        }
        __syncthreads();
    }

    const float oscale = (mat == 0) ? QSCALE : 1.0f;
    #pragma unroll
    for (int mi = 0; mi < 4; ++mi) {
        const int mrow = m0 + wm * 64 + mi * 16 + lg * 4;
        const int b = mrow >> 11;
        const int s = mrow & (S_LEN - 1);
        #pragma unroll
        for (int ni = 0; ni < 4; ++ni) {
            const int n = nb + wn * 64 + ni * 16 + lr;
            const int h = n >> 6;
            const int e = n & 63;
            if (mat == 2) {
                bf16x4 pk;
                #pragma unroll
                for (int r = 0; r < 4; ++r) pk[r] = (__bf16)acc[mi][ni][r];
                *reinterpret_cast<bf16x4*>(
                    vto + ((size_t)(b * NHEAD + h) * HDIM + e) * S_LEN + s) = pk;
            } else {
                __bf16* __restrict__ dst = (mat == 0) ? qo : ko;
                #pragma unroll
                for (int r = 0; r < 4; ++r)
                    dst[((size_t)(b * NHEAD + h) * S_LEN + (s + r)) * HDIM + e] =
                        (__bf16)(acc[mi][ni][r] * oscale);
            }
        }
    }
}

// ---------------------------------------------------------------------------
// One KV iteration (64 kv positions) for a QUAD of 16-row q-tiles.
// Branch-free body (mask only in the peeled MASK instantiation).
// K/V fragments shared across the 4 tiles: 16 loads feed 64 MFMAs.
// ---------------------------------------------------------------------------
template<bool MASK>
__device__ __attribute__((always_inline)) inline void quad_iter(
    int kv0, int qbase, int lr, int lg, int lk, int swz,
    const __bf16* __restrict__ kp, const __bf16* __restrict__ vp,
    const bf16x8 (&bq0)[4], const bf16x8 (&bq1)[4],
    float (&m_acc)[4], float (&l_acc)[4], f32x4 (&acc)[4][4],
    __bf16* pl_base)
{
    // ---- shared K fragments ----
    bf16x8 ka0[4], ka1[4];
    #pragma unroll
    for (int c = 0; c < 4; ++c) {
        const __bf16* krow = kp + (size_t)(kv0 + c * 16 + lr) * HDIM;
        ka0[c] = *reinterpret_cast<const bf16x8*>(krow + lk);
        ka1[c] = *reinterpret_cast<const bf16x8*>(krow + 32 + lk);
    }
    // ---- shared V fragments (hoisted: in flight during softmax) ----
    bf16x8 av[2][4];
    #pragma unroll
    for (int c2 = 0; c2 < 2; ++c2)
        #pragma unroll
        for (int ni = 0; ni < 4; ++ni)
            av[c2][ni] = *reinterpret_cast<const bf16x8*>(
                vp + (size_t)(ni * 16 + lr) * S_LEN + kv0 + c2 * 32 + lk);

    // ---- per-tile QK^T + branch-free online softmax ----
    #pragma unroll
    for (int i = 0; i < 4; ++i) {
        __bf16* pl = pl_base + i * (16 * 64);
        f32x4 s[4];
        __builtin_amdgcn_s_setprio(1);
        #pragma unroll
        for (int c = 0; c < 4; ++c) {
            f32x4 tt = {};
            tt = __builtin_amdgcn_mfma_f32_16x16x32_bf16(ka0[c], bq0[i], tt, 0, 0, 0);
            tt = __builtin_amdgcn_mfma_f32_16x16x32_bf16(ka1[c], bq1[i], tt, 0, 0, 0);
            s[c] = tt;
        }
        __builtin_amdgcn_s_setprio(0);

        if (MASK) {
            const int qrow = qbase + i * 16 + lr;
            #pragma unroll
            for (int c = 0; c < 4; ++c)
                #pragma unroll
                for (int r = 0; r < 4; ++r)
                    if (kv0 + c * 16 + lg * 4 + r > qrow) s[c][r] = -1e30f;
        }

        float a0 = fmaxf(fmaxf(s[0][0], s[0][1]), fmaxf(s[0][2], s[0][3]));
        float a1 = fmaxf(fmaxf(s[1][0], s[1][1]), fmaxf(s[1][2], s[1][3]));
        float a2 = fmaxf(fmaxf(s[2][0], s[2][1]), fmaxf(s[2][2], s[2][3]));
        float a3 = fmaxf(fmaxf(s[3][0], s[3][1]), fmaxf(s[3][2], s[3][3]));
        float mx = fmaxf(fmaxf(a0, a1), fmaxf(a2, a3));
        mx = fmaxf(mx, __shfl_xor(mx, 16));
        mx = fmaxf(mx, __shfl_xor(mx, 32));

        const float mnew = fmaxf(m_acc[i], mx);
        const float sc = exp2f(m_acc[i] - mnew);
        m_acc[i] = mnew;

        float psum = 0.0f;
        #pragma unroll
        for (int c = 0; c < 4; ++c) {
            const float p0 = exp2f(s[c][0] - mnew);
            const float p1 = exp2f(s[c][1] - mnew);
            const float p2 = exp2f(s[c][2] - mnew);
            const float p3 = exp2f(s[c][3] - mnew);
            psum += (p0 + p1) + (p2 + p3);
            uint2 pk;
            pk.x = bf16_bits(p0) | (bf16_bits(p1) << 16);
            pk.y = bf16_bits(p2) | (bf16_bits(p3) << 16);
            *reinterpret_cast<uint2*>(pl + lr * 64 + ((c * 16 + lg * 4) ^ swz)) = pk;
        }
        psum += __shfl_xor(psum, 16);
        psum += __shfl_xor(psum, 32);
        l_acc[i] = l_acc[i] * sc + psum;

        #pragma unroll
        for (int ni = 0; ni < 4; ++ni) acc[i][ni] *= sc;   // per-lane q-row
    }

    // ---- PV (swapped): shared V fragments, acc cols = own q-row ----
    __builtin_amdgcn_s_setprio(1);
    #pragma unroll
    for (int c2 = 0; c2 < 2; ++c2) {
        #pragma unroll
        for (int i = 0; i < 4; ++i) {
            __bf16* pl = pl_base + i * (16 * 64);
            const bf16x8 pa = *reinterpret_cast<const bf16x8*>(
                pl + lr * 64 + ((c2 * 32 + lk) ^ swz));
            #pragma unroll
            for (int ni = 0; ni < 4; ++ni)
                acc[i][ni] = __builtin_amdgcn_mfma_f32_16x16x32_bf16(
                    av[c2][ni], pa, acc[i][ni], 0, 0, 0);
        }
    }
    __builtin_amdgcn_s_setprio(0);
}

// ---------------------------------------------------------------------------
// Causal flash attention: QUAD of 16-row q-tiles (64 rows) per 1-wave block.
// All 4 tiles need the same q+1 KV iterations (quad spans one 64-band) ->
// zero wasted MFMA; K/V loads amortized 4x; 4 independent softmax chains
// give intra-wave ILP (R4/R6 evidence: ILP > TLP for this latency-bound
// loop). Last iteration peeled for branch-free hot loop. Grid 2048 waves =
// 8 blocks/CU all-resident; same-CU quads span the size range (balanced).
// ---------------------------------------------------------------------------
__global__ __launch_bounds__(64, 2) void attn_kernel(
    const __bf16* __restrict__ q, const __bf16* __restrict__ k,
    const __bf16* __restrict__ vt, float* __restrict__ out)
{
    __shared__ __bf16 plds[4][16][64];

    const int l  = threadIdx.x;
    const int lr = l & 15;
    const int lg = l >> 4;
    const int lk = lg * 8;
    const int swz = (lr & 7) << 3;

    // decode: xcd-pinned heads; quads descending (longest first)
    const int n   = blockIdx.x;
    const int xcd = n & 7;
    const int m   = n >> 3;              // 0..255
    const int qq  = 31 - (m >> 3);       // quad index
    const int bh  = xcd * 8 + (m & 7);

    const __bf16* __restrict__ kp = k  + (size_t)bh * S_LEN * HDIM;
    const __bf16* __restrict__ vp = vt + (size_t)bh * HDIM * S_LEN;
    const int bq = bh >> 4;
    const int hq = bh & 15;

    const int qbase = qq * 64;
    const int iters = qq + 1;

    // Q fragments for all 4 tiles (B-layout: col = lr = q row, k = e)
    const __bf16* __restrict__ qp = q + ((size_t)bh * S_LEN + qbase) * HDIM;
    bf16x8 bq0[4], bq1[4];
    #pragma unroll
    for (int i = 0; i < 4; ++i) {
        bq0[i] = *reinterpret_cast<const bf16x8*>(qp + (size_t)(i * 16 + lr) * HDIM + lk);
        bq1[i] = *reinterpret_cast<const bf16x8*>(qp + (size_t)(i * 16 + lr) * HDIM + 32 + lk);
    }

    float m_acc[4], l_acc[4];
    f32x4 acc[4][4] = {};
    #pragma unroll
    for (int i = 0; i < 4; ++i) { m_acc[i] = -1e30f; l_acc[i] = 0.0f; }

    __bf16* pl_base = &plds[0][0][0];

    #pragma unroll 1
    for (int j = 0; j < iters - 1; ++j)
        quad_iter<false>(j * 64, qbase, lr, lg, lk, swz, kp, vp,
                         bq0, bq1, m_acc, l_acc, acc, pl_base);
    quad_iter<true>((iters - 1) * 64, qbase, lr, lg, lk, swz, kp, vp,
                    bq0, bq1, m_acc, l_acc, acc, pl_base);

    // ---- epilogue: tile i, lane's q-row = qbase + 16i + lr ----
    #pragma unroll
    for (int i = 0; i < 4; ++i) {
        const float liv = 1.0f / l_acc[i];
        float* orow = out + (size_t)(bq * S_LEN + qbase + i * 16 + lr) * D_DIM + hq * HDIM;
        #pragma unroll
        for (int ni = 0; ni < 4; ++ni) {
            f32x4 ox;
            #pragma unroll
            for (int r = 0; r < 4; ++r) ox[r] = acc[i][ni][r] * liv;
            *reinterpret_cast<f32x4*>(orow + ni * 16 + lg * 4) = ox;
        }
    }
}

extern "C" void kernel_launch(void* const* d_in, const int* in_sizes, int n_in,
                              void* d_out, int out_size, void* d_ws, size_t ws_size,
                              hipStream_t stream)
{
    const float* x  = (const float*)d_in[0];
    const float* Wq = (const float*)d_in[1];
    const float* Wk = (const float*)d_in[2];
    const float* Wv = (const float*)d_in[3];
    float* out = (float*)d_out;

    const size_t x_elems = (size_t)BATCH * S_LEN * D_DIM;
    const size_t w_elems = (size_t)D_DIM * D_DIM;
    __bf16* xb   = (__bf16*)d_out;          // scratch in d_out (overwritten)
    __bf16* wcat = xb + x_elems;

    const size_t per_buf = (size_t)BATCH * NHEAD * S_LEN * HDIM;
    __bf16* qb = (__bf16*)d_ws;
    __bf16* kb = qb + per_buf;
    __bf16* vb = kb + per_buf;

    cvt_kernel<<<(int)(x_elems / 8 / 256), 256, 0, stream>>>(x, xb, (int)(x_elems / 8));
    cvt_kernel<<<(int)(w_elems / 8 / 256), 256, 0, stream>>>(Wq, wcat, (int)(w_elems / 8));
    cvt_kernel<<<(int)(w_elems / 8 / 256), 256, 0, stream>>>(Wk, wcat + w_elems, (int)(w_elems / 8));
    cvt_kernel<<<(int)(w_elems / 8 / 256), 256, 0, stream>>>(Wv, wcat + 2 * w_elems, (int)(w_elems / 8));

    dim3 grid1(3 * D_DIM / 128, (BATCH * S_LEN) / 128);   // (24, 64)
    proj_gemm_kernel<<<grid1, dim3(256), 0, stream>>>(xb, wcat, qb, kb, vb);

    attn_kernel<<<dim3(2048), dim3(64), 0, stream>>>(qb, kb, vb, out);
}